// Round 5
// baseline (6427.604 us; speedup 1.0000x reference)
//
#include <hip/hip_runtime.h>
#include <hip/hip_bf16.h>
#include <math.h>

#define DIMD 512
#define SEQL 4096
#define KU 1024
#define KF 1536
#define NJ 8192
#define KC 384          // OpenBLAS sgemm K-blocking (Zen/Haswell SGEMM_DEFAULT_Q)

#define BM 64
#define BK 32
#define PA 33
#define PW 68

// f32 R with OpenBLAS-emulated chunked fma chain (k-ascending, KC blocks)
__device__ __forceinline__ float chainR(
    const float* __restrict__ h, const float* __restrict__ us, const float* __restrict__ ue,
    const float* __restrict__ Wr, const float* __restrict__ br, int o)
{
    float accT = 0.f;
    for (int k0 = 0; k0 < 2560; k0 += KC) {
        int ke = (k0 + KC < 2560) ? k0 + KC : 2560;
        float accC = 0.f;
        for (int k = k0; k < ke; ++k) {
            float xv = (k < 1536) ? h[k] : (k < 2048) ? us[k - 1536] : ue[k - 2048];
            accC = fmaf(xv, Wr[(size_t)o * 2560 + k], accC);
        }
        accT = __fadd_rn(accT, accC);   // adding to +0.0 first time is exact
    }
    return __fadd_rn(accT, br[o]);
}

__global__ __launch_bounds__(256) void k_R32(
    const float* __restrict__ h, const float* __restrict__ us, const float* __restrict__ ue,
    const float* __restrict__ Wr, const float* __restrict__ br, float* __restrict__ Rout)
{
    int o = blockIdx.x * 256 + threadIdx.x;   // grid 2 -> o in [0,512)
    Rout[o] = chainR(h, us, ue, Wr, br, o);
}

// ---------------- main fused kernel: f32 OpenBLAS-emulated m, f64 epilogue ----------------
// MODE 1: R_f32 from d_ws. MODE 2: ws-free, R computed per block.
template <int MODE>
__global__ __launch_bounds__(256) void k_main4(
    const float* __restrict__ u, const float* __restrict__ noise,
    const float* __restrict__ Wnn, const float* __restrict__ Wno, const float* __restrict__ WE,
    const float* __restrict__ bnn, const float* __restrict__ bno, const float* __restrict__ bE,
    const float* __restrict__ h, const float* __restrict__ us, const float* __restrict__ ue,
    const float* __restrict__ Wr, const float* __restrict__ br,
    const float* __restrict__ Rws,
    float* __restrict__ out)
{
    __shared__ __align__(16) float As[BM][PA];        // u tile [s-row][k]
    __shared__ __align__(16) float Ws[3][BK][PW];     // [mat][k][col], k-major
    __shared__ float Rsh[512];

    const int tid = threadIdx.x;
    const int sr = tid >> 2;                 // 0..63 : s-row in tile
    const int dl = tid & 3;                  // 0..3  : d in tile
    const int jBase = blockIdx.x * 64;
    const int sBase = blockIdx.y * BM;
    const int myCol = dl * 16;

    if (MODE == 1) {
        for (int i = tid; i < 512; i += 256) Rsh[i] = Rws[i];
    } else {
        for (int o = tid; o < 512; o += 256) Rsh[o] = chainR(h, us, ue, Wr, br, o);
    }

    // chunked f32 chains: t = running total (f32 adds at KC boundaries), c = current chunk
    float t1[16] = {}, c1[16] = {}, t2[16] = {}, c2[16] = {}, tE[16] = {}, cE[16] = {};

    for (int kt = 0; kt < KF; kt += BK) {
        __syncthreads();
        if (kt < KU) {
            for (int idx = tid; idx < BM * BK; idx += 256) {
                int r = idx >> 5, c = idx & 31;
                As[r][c] = u[(size_t)(sBase + r) * KU + kt + c];
            }
        }
        for (int idx = tid; idx < 64 * BK; idx += 256) {
            int col = idx >> 5, kk = idx & 31;
            size_t off = (size_t)(jBase + col) * KF + kt + kk;
            Ws[0][kk][col] = Wnn[off];
            Ws[1][kk][col] = Wno[off];
            Ws[2][kk][col] = WE[off];
        }
        __syncthreads();
        const bool uReg = (kt < KU);
        for (int kk = 0; kk < BK; ++kk) {
            float a = uReg ? As[sr][kk] : Rsh[kt + kk - KU];
            #pragma unroll
            for (int q = 0; q < 4; ++q) {
                float4 w0 = *(const float4*)&Ws[0][kk][myCol + 4 * q];
                float4 w1 = *(const float4*)&Ws[1][kk][myCol + 4 * q];
                float4 w2 = *(const float4*)&Ws[2][kk][myCol + 4 * q];
                c1[4*q+0] = fmaf(a, w0.x, c1[4*q+0]);
                c1[4*q+1] = fmaf(a, w0.y, c1[4*q+1]);
                c1[4*q+2] = fmaf(a, w0.z, c1[4*q+2]);
                c1[4*q+3] = fmaf(a, w0.w, c1[4*q+3]);
                c2[4*q+0] = fmaf(a, w1.x, c2[4*q+0]);
                c2[4*q+1] = fmaf(a, w1.y, c2[4*q+1]);
                c2[4*q+2] = fmaf(a, w1.z, c2[4*q+2]);
                c2[4*q+3] = fmaf(a, w1.w, c2[4*q+3]);
                cE[4*q+0] = fmaf(a, w2.x, cE[4*q+0]);
                cE[4*q+1] = fmaf(a, w2.y, cE[4*q+1]);
                cE[4*q+2] = fmaf(a, w2.z, cE[4*q+2]);
                cE[4*q+3] = fmaf(a, w2.w, cE[4*q+3]);
            }
        }
        if (((kt + BK) % KC) == 0 || (kt + BK) == KF) {   // fold chunk at KC boundaries + end
            #pragma unroll
            for (int e = 0; e < 16; ++e) {
                t1[e] = __fadd_rn(t1[e], c1[e]); c1[e] = 0.f;
                t2[e] = __fadd_rn(t2[e], c2[e]); c2[e] = 0.f;
                tE[e] = __fadd_rn(tE[e], cE[e]); cE[e] = 0.f;
            }
        }
    }

    // ---- epilogue: f32 m exactly as numpy; selection + softmax in f64 ----
    const int s = sBase + sr;
    const int jb = jBase + myCol;
    float m32[16]; double evv[16];
    #pragma unroll
    for (int e = 0; e < 16; ++e) {
        float h1 = __fadd_rn(t1[e], bnn[jb + e]);
        float h2 = __fadd_rn(t2[e], bno[jb + e]);
        float nz = noise[(size_t)s * NJ + jb + e];
        m32[e] = __fadd_rn(h1, __fmul_rn(h2, nz));
        evv[e] = (double)__fadd_rn(tE[e], bE[jb + e]);
    }
    // top-2 on the f32 values (ties -> lowest index, matching top_k)
    int i1 = 0; float v1 = m32[0];
    #pragma unroll
    for (int e = 1; e < 16; ++e) if (m32[e] > v1) { v1 = m32[e]; i1 = e; }
    int i2 = -1; float v2 = -INFINITY;
    #pragma unroll
    for (int e = 0; e < 16; ++e) if (e != i1 && m32[e] > v2) { v2 = m32[e]; i2 = e; }
    double e1 = 0.0, e2 = 0.0, sumE = 0.0;
    #pragma unroll
    for (int e = 0; e < 16; ++e) {
        e1 = (e == i1) ? evv[e] : e1;
        e2 = (e == i2) ? evv[e] : e2;
        sumE += evv[e];
    }
    // faithful semantics: selected entries that are exactly 0 also get -1e5
    double x1 = (v1 == 0.0f) ? -100000.0 : (double)v1;
    double x2 = (v2 == 0.0f) ? -100000.0 : (double)v2;
    double vmax = fmax(fmax(x1, x2), -100000.0);
    double g1 = exp(x1 - vmax), g2 = exp(x2 - vmax), gz = exp(-100000.0 - vmax);
    double den = g1 + g2 + 14.0 * gz;
    double num = g1 * e1 + g2 * e2 + gz * (sumE - e1 - e2);
    out[(size_t)s * DIMD + (jBase >> 4) + dl] = (float)(num / den * 0.0625);
}

extern "C" void kernel_launch(void* const* d_in, const int* in_sizes, int n_in,
                              void* d_out, int out_size, void* d_ws, size_t ws_size,
                              hipStream_t stream) {
    (void)in_sizes; (void)n_in; (void)out_size;
    const float* h     = (const float*)d_in[0];
    const float* us    = (const float*)d_in[1];
    const float* ue    = (const float*)d_in[2];
    const float* u     = (const float*)d_in[3];
    const float* noise = (const float*)d_in[4];
    const float* Wnn   = (const float*)d_in[5];
    const float* bnn   = (const float*)d_in[6];
    const float* Wno   = (const float*)d_in[7];
    const float* bno   = (const float*)d_in[8];
    const float* WE    = (const float*)d_in[9];
    const float* bE    = (const float*)d_in[10];
    const float* Wr    = (const float*)d_in[11];
    const float* br    = (const float*)d_in[12];
    float* out = (float*)d_out;

    if (ws_size >= 512 * sizeof(float)) {
        float* Rws = (float*)d_ws;
        hipLaunchKernelGGL(k_R32, dim3(2), dim3(256), 0, stream, h, us, ue, Wr, br, Rws);
        hipLaunchKernelGGL((k_main4<1>), dim3(NJ / 64, SEQL / BM), dim3(256), 0, stream,
                           u, noise, Wnn, Wno, WE, bnn, bno, bE,
                           h, us, ue, Wr, br, (const float*)Rws, out);
    } else {
        hipLaunchKernelGGL((k_main4<2>), dim3(NJ / 64, SEQL / BM), dim3(256), 0, stream,
                           u, noise, Wnn, Wno, WE, bnn, bno, bE,
                           h, us, ue, Wr, br, (const float*)nullptr, out);
    }
}

// Round 6
// 3971.729 us; speedup vs baseline: 1.6183x; 1.6183x over previous
//
#include <hip/hip_runtime.h>
#include <hip/hip_bf16.h>
#include <math.h>

#define DIMD 512
#define SEQL 4096
#define KU 1024
#define KF 1536
#define NJ 8192
#define KC 384          // OpenBLAS sgemm K-blocking (matched in round 5)

#define BM 64
#define BK 32
#define PA 33
#define PW 68

#define WS_C4_OFF 4096
#define WS_E_OFF  (128 * 1024)
#define WS_NEEDED (WS_E_OFF + (size_t)SEQL * NJ * 4)

typedef __attribute__((ext_vector_type(8))) short bf16x8;
typedef __attribute__((ext_vector_type(4))) float f32x4;

__device__ __forceinline__ ushort f2bf(float f) {
    __hip_bfloat16 h = __float2bfloat16(f);
    return *reinterpret_cast<ushort*>(&h);
}

// ---- f32 R with the exact chunked fma chain (k-ascending, KC blocks) ----
__device__ __forceinline__ float chainR(
    const float* __restrict__ h, const float* __restrict__ us, const float* __restrict__ ue,
    const float* __restrict__ Wr, const float* __restrict__ br, int o)
{
    float accT = 0.f;
    for (int k0 = 0; k0 < 2560; k0 += KC) {
        int ke = (k0 + KC < 2560) ? k0 + KC : 2560;
        float accC = 0.f;
        for (int k = k0; k < ke; ++k) {
            float xv = (k < 1536) ? h[k] : (k < 2048) ? us[k - 1536] : ue[k - 2048];
            accC = fmaf(xv, Wr[(size_t)o * 2560 + k], accC);
        }
        accT = __fadd_rn(accT, accC);
    }
    return __fadd_rn(accT, br[o]);
}

__global__ __launch_bounds__(256) void k_R32(
    const float* __restrict__ h, const float* __restrict__ us, const float* __restrict__ ue,
    const float* __restrict__ Wr, const float* __restrict__ br, float* __restrict__ Rout)
{
    int o = blockIdx.x * 256 + threadIdx.x;
    Rout[o] = chainR(h, us, ue, Wr, br, o);
}

// ---- chunk-4 precompute: c4[mat][j] = f32 chain over k in [1152,1536) ----
__global__ __launch_bounds__(256) void k_c4(
    const float* __restrict__ R32, const float* __restrict__ Wnn,
    const float* __restrict__ Wno, float* __restrict__ c4)
{
    int idx = blockIdx.x * 256 + threadIdx.x;    // 0..16383
    int mat = idx >> 13, j = idx & 8191;
    const float* W = mat ? Wno : Wnn;
    float c = 0.f;
    for (int k = 1152; k < 1536; ++k)
        c = fmaf(R32[k - KU], W[(size_t)j * KF + k], c);
    c4[idx] = c;
}

// ---- E-path: e = x @ W_E^T + b_E via bf16 MFMA, f32 out to ws ----
#define EB 128
#define EPAD 40
__global__ __launch_bounds__(256) void k_e(
    const float* __restrict__ u, const float* __restrict__ R32,
    const float* __restrict__ WE, const float* __restrict__ bE,
    float* __restrict__ eout)
{
    __shared__ ushort Asb[EB][EPAD];   // x tile, bf16 bits, K-major rows
    __shared__ ushort Bsb[EB][EPAD];   // W_E tile
    const int tid = threadIdx.x;
    const int w = tid >> 6, l = tid & 63;
    const int wm = w >> 1, wn = w & 1;
    const int sBase = blockIdx.y * EB;
    const int jBase = blockIdx.x * EB;

    f32x4 acc[4][4] = {};

    for (int kt = 0; kt < KF; kt += BK) {
        __syncthreads();
        #pragma unroll
        for (int it = 0; it < 4; ++it) {
            int idx = tid + it * 256;                  // 1024 float4 slots
            int row = idx >> 3, c4o = (idx & 7) << 2;
            float4 v;
            if (kt < KU) v = *(const float4*)&u[(size_t)(sBase + row) * KU + kt + c4o];
            else         v = *(const float4*)&R32[kt - KU + c4o];
            ushort4 o;
            o.x = f2bf(v.x); o.y = f2bf(v.y); o.z = f2bf(v.z); o.w = f2bf(v.w);
            *(ushort4*)&Asb[row][c4o] = o;
        }
        #pragma unroll
        for (int it = 0; it < 4; ++it) {
            int idx = tid + it * 256;
            int col = idx >> 3, c4o = (idx & 7) << 2;
            float4 v = *(const float4*)&WE[(size_t)(jBase + col) * KF + kt + c4o];
            ushort4 o;
            o.x = f2bf(v.x); o.y = f2bf(v.y); o.z = f2bf(v.z); o.w = f2bf(v.w);
            *(ushort4*)&Bsb[col][c4o] = o;
        }
        __syncthreads();
        const int kq = (l >> 4) << 3;
        bf16x8 af[4], bff[4];
        #pragma unroll
        for (int i = 0; i < 4; ++i)
            af[i] = *(const bf16x8*)&Asb[wm * 64 + i * 16 + (l & 15)][kq];
        #pragma unroll
        for (int n = 0; n < 4; ++n)
            bff[n] = *(const bf16x8*)&Bsb[wn * 64 + n * 16 + (l & 15)][kq];
        #pragma unroll
        for (int i = 0; i < 4; ++i)
            #pragma unroll
            for (int n = 0; n < 4; ++n)
                acc[i][n] = __builtin_amdgcn_mfma_f32_16x16x32_bf16(af[i], bff[n], acc[i][n], 0, 0, 0);
    }
    // epilogue: C row = (lane>>4)*4 + reg, col = lane&15 (m89-verified layout)
    #pragma unroll
    for (int i = 0; i < 4; ++i) {
        int row = sBase + wm * 64 + i * 16 + ((l >> 4) << 2);
        #pragma unroll
        for (int n = 0; n < 4; ++n) {
            int col = jBase + wn * 64 + n * 16 + (l & 15);
            float bb = bE[col];
            #pragma unroll
            for (int r = 0; r < 4; ++r)
                eout[(size_t)(row + r) * NJ + col] = acc[i][n][r] + bb;
        }
    }
}

// ---- fast m-path: 2-mat exact f32 chains over k in [0,1152) + c4 fold ----
__global__ __launch_bounds__(256, 4) void k_fast(
    const float* __restrict__ u, const float* __restrict__ noise,
    const float* __restrict__ Wnn, const float* __restrict__ Wno,
    const float* __restrict__ bnn, const float* __restrict__ bno,
    const float* __restrict__ Rws, const float* __restrict__ c4ws,
    const float* __restrict__ ews, float* __restrict__ out)
{
    __shared__ __align__(16) float As[BM][PA];
    __shared__ __align__(16) float Ws[2][BK][PW];
    __shared__ float Rsh[128];

    const int tid = threadIdx.x;
    const int sr = tid >> 2, dl = tid & 3;
    const int jBase = blockIdx.x * 64;
    const int sBase = blockIdx.y * BM;
    const int myCol = dl * 16;

    for (int i = tid; i < 128; i += 256) Rsh[i] = Rws[i];

    float t1[16] = {}, c1[16] = {}, t2[16] = {}, c2[16] = {};

    for (int kt = 0; kt < 1152; kt += BK) {
        __syncthreads();
        if (kt < KU) {
            for (int idx = tid; idx < BM * BK; idx += 256) {
                int r = idx >> 5, c = idx & 31;
                As[r][c] = u[(size_t)(sBase + r) * KU + kt + c];
            }
        }
        for (int idx = tid; idx < 2 * 64 * BK; idx += 256) {
            int m = idx >> 11, rem = idx & 2047;
            int col = rem >> 5, kk = rem & 31;
            const float* W = m ? Wno : Wnn;
            Ws[m][kk][col] = W[(size_t)(jBase + col) * KF + kt + kk];
        }
        __syncthreads();
        const bool uReg = (kt < KU);
        for (int kk = 0; kk < BK; ++kk) {
            float a = uReg ? As[sr][kk] : Rsh[kt + kk - KU];
            #pragma unroll
            for (int q = 0; q < 4; ++q) {
                float4 w0 = *(const float4*)&Ws[0][kk][myCol + 4 * q];
                float4 w1 = *(const float4*)&Ws[1][kk][myCol + 4 * q];
                c1[4*q+0] = fmaf(a, w0.x, c1[4*q+0]);
                c1[4*q+1] = fmaf(a, w0.y, c1[4*q+1]);
                c1[4*q+2] = fmaf(a, w0.z, c1[4*q+2]);
                c1[4*q+3] = fmaf(a, w0.w, c1[4*q+3]);
                c2[4*q+0] = fmaf(a, w1.x, c2[4*q+0]);
                c2[4*q+1] = fmaf(a, w1.y, c2[4*q+1]);
                c2[4*q+2] = fmaf(a, w1.z, c2[4*q+2]);
                c2[4*q+3] = fmaf(a, w1.w, c2[4*q+3]);
            }
        }
        if (((kt + BK) % KC) == 0) {    // folds at 384, 768, 1152
            #pragma unroll
            for (int e = 0; e < 16; ++e) {
                t1[e] = __fadd_rn(t1[e], c1[e]); c1[e] = 0.f;
                t2[e] = __fadd_rn(t2[e], c2[e]); c2[e] = 0.f;
            }
        }
    }

    const int s = sBase + sr;
    const int jb = jBase + myCol;
    float m32[16]; double evv[16];
    #pragma unroll
    for (int e = 0; e < 16; ++e) {
        float T1 = __fadd_rn(t1[e], c4ws[jb + e]);          // fold chunk 4 (bit-exact)
        float T2 = __fadd_rn(t2[e], c4ws[NJ + jb + e]);
        float h1 = __fadd_rn(T1, bnn[jb + e]);
        float h2 = __fadd_rn(T2, bno[jb + e]);
        float nz = noise[(size_t)s * NJ + jb + e];
        m32[e] = __fadd_rn(h1, __fmul_rn(h2, nz));
        evv[e] = (double)ews[(size_t)s * NJ + jb + e];
    }
    int i1 = 0; float v1 = m32[0];
    #pragma unroll
    for (int e = 1; e < 16; ++e) if (m32[e] > v1) { v1 = m32[e]; i1 = e; }
    int i2 = -1; float v2 = -INFINITY;
    #pragma unroll
    for (int e = 0; e < 16; ++e) if (e != i1 && m32[e] > v2) { v2 = m32[e]; i2 = e; }
    double e1 = 0.0, e2 = 0.0, sumE = 0.0;
    #pragma unroll
    for (int e = 0; e < 16; ++e) {
        e1 = (e == i1) ? evv[e] : e1;
        e2 = (e == i2) ? evv[e] : e2;
        sumE += evv[e];
    }
    double x1 = (v1 == 0.0f) ? -100000.0 : (double)v1;
    double x2 = (v2 == 0.0f) ? -100000.0 : (double)v2;
    double vmax = fmax(fmax(x1, x2), -100000.0);
    double g1 = exp(x1 - vmax), g2 = exp(x2 - vmax), gz = exp(-100000.0 - vmax);
    double den = g1 + g2 + 14.0 * gz;
    double num = g1 * e1 + g2 * e2 + gz * (sumE - e1 - e2);
    out[(size_t)s * DIMD + (jBase >> 4) + dl] = (float)(num / den * 0.0625);
}

// ---- fallback: proven round-5 ws-free kernel (bit-identical arithmetic) ----
__global__ __launch_bounds__(256) void k_base(
    const float* __restrict__ u, const float* __restrict__ noise,
    const float* __restrict__ Wnn, const float* __restrict__ Wno, const float* __restrict__ WE,
    const float* __restrict__ bnn, const float* __restrict__ bno, const float* __restrict__ bE,
    const float* __restrict__ h, const float* __restrict__ us, const float* __restrict__ ue,
    const float* __restrict__ Wr, const float* __restrict__ br,
    float* __restrict__ out)
{
    __shared__ __align__(16) float As[BM][PA];
    __shared__ __align__(16) float Ws[3][BK][PW];
    __shared__ float Rsh[512];

    const int tid = threadIdx.x;
    const int sr = tid >> 2, dl = tid & 3;
    const int jBase = blockIdx.x * 64;
    const int sBase = blockIdx.y * BM;
    const int myCol = dl * 16;

    for (int o = tid; o < 512; o += 256) Rsh[o] = chainR(h, us, ue, Wr, br, o);

    float t1[16] = {}, c1[16] = {}, t2[16] = {}, c2[16] = {}, tE[16] = {}, cE[16] = {};

    for (int kt = 0; kt < KF; kt += BK) {
        __syncthreads();
        if (kt < KU) {
            for (int idx = tid; idx < BM * BK; idx += 256) {
                int r = idx >> 5, c = idx & 31;
                As[r][c] = u[(size_t)(sBase + r) * KU + kt + c];
            }
        }
        for (int idx = tid; idx < 64 * BK; idx += 256) {
            int col = idx >> 5, kk = idx & 31;
            size_t off = (size_t)(jBase + col) * KF + kt + kk;
            Ws[0][kk][col] = Wnn[off];
            Ws[1][kk][col] = Wno[off];
            Ws[2][kk][col] = WE[off];
        }
        __syncthreads();
        const bool uReg = (kt < KU);
        for (int kk = 0; kk < BK; ++kk) {
            float a = uReg ? As[sr][kk] : Rsh[kt + kk - KU];
            #pragma unroll
            for (int q = 0; q < 4; ++q) {
                float4 w0 = *(const float4*)&Ws[0][kk][myCol + 4 * q];
                float4 w1 = *(const float4*)&Ws[1][kk][myCol + 4 * q];
                float4 w2 = *(const float4*)&Ws[2][kk][myCol + 4 * q];
                c1[4*q+0] = fmaf(a, w0.x, c1[4*q+0]);
                c1[4*q+1] = fmaf(a, w0.y, c1[4*q+1]);
                c1[4*q+2] = fmaf(a, w0.z, c1[4*q+2]);
                c1[4*q+3] = fmaf(a, w0.w, c1[4*q+3]);
                c2[4*q+0] = fmaf(a, w1.x, c2[4*q+0]);
                c2[4*q+1] = fmaf(a, w1.y, c2[4*q+1]);
                c2[4*q+2] = fmaf(a, w1.z, c2[4*q+2]);
                c2[4*q+3] = fmaf(a, w1.w, c2[4*q+3]);
                cE[4*q+0] = fmaf(a, w2.x, cE[4*q+0]);
                cE[4*q+1] = fmaf(a, w2.y, cE[4*q+1]);
                cE[4*q+2] = fmaf(a, w2.z, cE[4*q+2]);
                cE[4*q+3] = fmaf(a, w2.w, cE[4*q+3]);
            }
        }
        if (((kt + BK) % KC) == 0 || (kt + BK) == KF) {
            #pragma unroll
            for (int e = 0; e < 16; ++e) {
                t1[e] = __fadd_rn(t1[e], c1[e]); c1[e] = 0.f;
                t2[e] = __fadd_rn(t2[e], c2[e]); c2[e] = 0.f;
                tE[e] = __fadd_rn(tE[e], cE[e]); cE[e] = 0.f;
            }
        }
    }

    const int s = sBase + sr;
    const int jb = jBase + myCol;
    float m32[16]; double evv[16];
    #pragma unroll
    for (int e = 0; e < 16; ++e) {
        float h1 = __fadd_rn(t1[e], bnn[jb + e]);
        float h2 = __fadd_rn(t2[e], bno[jb + e]);
        float nz = noise[(size_t)s * NJ + jb + e];
        m32[e] = __fadd_rn(h1, __fmul_rn(h2, nz));
        evv[e] = (double)__fadd_rn(tE[e], bE[jb + e]);
    }
    int i1 = 0; float v1 = m32[0];
    #pragma unroll
    for (int e = 1; e < 16; ++e) if (m32[e] > v1) { v1 = m32[e]; i1 = e; }
    int i2 = -1; float v2 = -INFINITY;
    #pragma unroll
    for (int e = 0; e < 16; ++e) if (e != i1 && m32[e] > v2) { v2 = m32[e]; i2 = e; }
    double e1 = 0.0, e2 = 0.0, sumE = 0.0;
    #pragma unroll
    for (int e = 0; e < 16; ++e) {
        e1 = (e == i1) ? evv[e] : e1;
        e2 = (e == i2) ? evv[e] : e2;
        sumE += evv[e];
    }
    double x1 = (v1 == 0.0f) ? -100000.0 : (double)v1;
    double x2 = (v2 == 0.0f) ? -100000.0 : (double)v2;
    double vmax = fmax(fmax(x1, x2), -100000.0);
    double g1 = exp(x1 - vmax), g2 = exp(x2 - vmax), gz = exp(-100000.0 - vmax);
    double den = g1 + g2 + 14.0 * gz;
    double num = g1 * e1 + g2 * e2 + gz * (sumE - e1 - e2);
    out[(size_t)s * DIMD + (jBase >> 4) + dl] = (float)(num / den * 0.0625);
}

extern "C" void kernel_launch(void* const* d_in, const int* in_sizes, int n_in,
                              void* d_out, int out_size, void* d_ws, size_t ws_size,
                              hipStream_t stream) {
    (void)in_sizes; (void)n_in; (void)out_size;
    const float* h     = (const float*)d_in[0];
    const float* us    = (const float*)d_in[1];
    const float* ue    = (const float*)d_in[2];
    const float* u     = (const float*)d_in[3];
    const float* noise = (const float*)d_in[4];
    const float* Wnn   = (const float*)d_in[5];
    const float* bnn   = (const float*)d_in[6];
    const float* Wno   = (const float*)d_in[7];
    const float* bno   = (const float*)d_in[8];
    const float* WE    = (const float*)d_in[9];
    const float* bE    = (const float*)d_in[10];
    const float* Wr    = (const float*)d_in[11];
    const float* br    = (const float*)d_in[12];
    float* out = (float*)d_out;

    if (ws_size >= WS_NEEDED) {
        float* Rws  = (float*)d_ws;
        float* c4ws = (float*)((char*)d_ws + WS_C4_OFF);
        float* ews  = (float*)((char*)d_ws + WS_E_OFF);
        hipLaunchKernelGGL(k_R32, dim3(2), dim3(256), 0, stream, h, us, ue, Wr, br, Rws);
        hipLaunchKernelGGL(k_c4, dim3(64), dim3(256), 0, stream, Rws, Wnn, Wno, c4ws);
        hipLaunchKernelGGL(k_e, dim3(NJ / EB, SEQL / EB), dim3(256), 0, stream,
                           u, Rws, WE, bE, ews);
        hipLaunchKernelGGL(k_fast, dim3(NJ / 64, SEQL / BM), dim3(256), 0, stream,
                           u, noise, Wnn, Wno, bnn, bno, Rws, c4ws, ews, out);
    } else {
        hipLaunchKernelGGL(k_base, dim3(NJ / 64, SEQL / BM), dim3(256), 0, stream,
                           u, noise, Wnn, Wno, WE, bnn, bno, bE,
                           h, us, ue, Wr, br, out);
    }
}